// Round 2
// baseline (298.611 us; speedup 1.0000x reference)
//
#include <hip/hip_runtime.h>

// PCEN: M[0]=x[0]; M[t]=(1-s)M[t-1]+s*x[t]; out=(x/(M+eps)^a + d)^r - d^r
// Shapes: x,out (64, 4000, 128) fp32.
// Strategy: chunk T into NCHUNK pieces; each chunk re-derives its carry-in
// via a WARM-step overlapped warmup (decay 0.975^384 ~ 6e-5 kills init error).
// Chunks whose warmup window clamps to t=0 are exact (they use the M[0]=x[0] rule).

#define B_DIM 64
#define T_DIM 4000
#define F_DIM 128
#define NCHUNK 16
#define CLEN 250        // NCHUNK*CLEN == T_DIM
#define WARM 384        // 0.975^384 ~ 6e-5 attenuation of warmup init error

__global__ __launch_bounds__(128) void pcen_kernel(const float* __restrict__ x,
                                                   float* __restrict__ out) {
    const float S      = 0.025f;
    const float OMS    = 0.975f;      // 1 - S
    const float EPS    = 1e-6f;
    const float NALPHA = -0.98f;      // -alpha
    const float DELTA  = 2.0f;
    const float SQRTD  = 1.41421356237f; // 2^0.5

    const int f  = threadIdx.x;       // 0..127, lane covers feature dim -> coalesced
    const int b  = blockIdx.x;        // 0..63
    const int ck = blockIdx.y;        // 0..NCHUNK-1
    const int t0 = ck * CLEN;

    const float* xb = x   + (b * T_DIM) * F_DIM + f;
    float*       ob = out + (b * T_DIM) * F_DIM + f;

    float M;
    int t = t0;

    if (ck == 0) {
        // Exact: M[0] = x[0], emit output for t=0, continue from t=1.
        float xv = xb[0];
        M = xv;
        float p = __builtin_amdgcn_exp2f(NALPHA * __builtin_amdgcn_logf(M + EPS));
        ob[0] = __builtin_sqrtf(__builtin_fmaf(xv, p, DELTA)) - SQRTD;
        t = 1;
    } else {
        // Overlapped warmup. If the window reaches t=0 this is exact
        // (init M = x[0] is the reference's own rule).
        int tw = t0 - WARM;
        if (tw < 0) tw = 0;
        M = xb[tw * F_DIM];
        #pragma unroll 4
        for (int u = tw + 1; u < t0; ++u) {
            M = __builtin_fmaf(OMS, M, S * xb[u * F_DIM]);
        }
    }

    const int tend = t0 + CLEN;
    #pragma unroll 4
    for (; t < tend; ++t) {
        float xv = xb[t * F_DIM];
        M = __builtin_fmaf(OMS, M, S * xv);
        // (M+eps)^-alpha = exp2(-alpha * log2(M+eps))
        float p = __builtin_amdgcn_exp2f(NALPHA * __builtin_amdgcn_logf(M + EPS));
        ob[t * F_DIM] = __builtin_sqrtf(__builtin_fmaf(xv, p, DELTA)) - SQRTD;
    }
}

extern "C" void kernel_launch(void* const* d_in, const int* in_sizes, int n_in,
                              void* d_out, int out_size, void* d_ws, size_t ws_size,
                              hipStream_t stream) {
    const float* x = (const float*)d_in[0];
    float* out = (float*)d_out;
    dim3 grid(B_DIM, NCHUNK);
    pcen_kernel<<<grid, 128, 0, stream>>>(x, out);
}

// Round 3
// 270.151 us; speedup vs baseline: 1.1053x; 1.1053x over previous
//
#include <hip/hip_runtime.h>

// PCEN: M[0]=x[0]; M[t]=(1-s)M[t-1]+s*x[t]; out=(x/(M+eps)^a + d)^r - d^r
// Shapes: x,out (64, 4000, 128) fp32.
//
// R3: latency-bound fix (R2 counters: VALUBusy 16%, Occ 16%, HBM 24% -> all low).
//  - NCHUNK 16->32 (serial path 634->381), WARM 384->256 (0.975^256 ~ 1.5e-3,
//    x sensitivity ~2 -> ~3e-3 added error vs 9.56e-2 threshold).
//  - 16 waves/CU (2048 blocks x 2 waves, ~50% occupancy).
//  - Explicit 5-deep rolling prefetch in main loop: 5 loads/thread in flight,
//    262k threads x 20 B = 5 MB in flight >> 1.6 MB Little's-law need.

#define B_DIM 64
#define T_DIM 4000
#define F_DIM 128
#define NCHUNK 32
#define CLEN 125        // NCHUNK*CLEN == T_DIM
#define WARM 256        // 0.975^256 ~ 1.5e-3 attenuation of warmup init error
#define PF 5            // prefetch depth; CLEN = 25*PF

__global__ __launch_bounds__(128) void pcen_kernel(const float* __restrict__ x,
                                                   float* __restrict__ out) {
    const float S      = 0.025f;
    const float OMS    = 0.975f;         // 1 - S
    const float EPS    = 1e-6f;
    const float NALPHA = -0.98f;         // -alpha
    const float DELTA  = 2.0f;
    const float SQRTD  = 1.41421356237f; // 2^0.5

    const int f  = threadIdx.x;          // 0..127: lane = feature -> coalesced
    const int b  = blockIdx.x;           // 0..63
    const int ck = blockIdx.y;           // 0..NCHUNK-1
    const int t0 = ck * CLEN;

    const float* xb = x   + (b * T_DIM) * F_DIM + f;
    float*       ob = out + (b * T_DIM) * F_DIM + f;

    // ---- warmup: re-derive carry-in. Clamped-to-0 windows are exact
    // (M_init = x[0] is the reference's own rule; for ck==0 the first main
    // step computes 0.975*x0 + 0.025*x0 = x0 to 1 ulp).
    int tw = t0 - WARM;
    if (tw < 0) tw = 0;
    float M = xb[tw * F_DIM];
    #pragma unroll 8
    for (int u = tw + 1; u < t0; ++u) {
        M = __builtin_fmaf(OMS, M, S * xb[u * F_DIM]);
    }

    // ---- main loop with rolling PF-deep prefetch
    float buf[PF];
    #pragma unroll
    for (int u = 0; u < PF; ++u) {
        buf[u] = xb[(t0 + u) * F_DIM];
    }

    for (int g = 0; g < CLEN / PF; ++g) {   // 25 groups of 5
        const int tb = t0 + g * PF;
        #pragma unroll
        for (int u = 0; u < PF; ++u) {
            const int t = tb + u;
            float xv = buf[u];
            M = __builtin_fmaf(OMS, M, S * xv);
            // (M+eps)^-alpha = exp2(-alpha * log2(M+eps))
            float p = __builtin_amdgcn_exp2f(NALPHA * __builtin_amdgcn_logf(M + EPS));
            ob[t * F_DIM] = __builtin_sqrtf(__builtin_fmaf(xv, p, DELTA)) - SQRTD;
            // prefetch t+PF (clamp: last chunk would run past the array)
            int tn = t + PF;
            tn = tn < T_DIM - 1 ? tn : T_DIM - 1;
            buf[u] = xb[tn * F_DIM];
        }
    }
}

extern "C" void kernel_launch(void* const* d_in, const int* in_sizes, int n_in,
                              void* d_out, int out_size, void* d_ws, size_t ws_size,
                              hipStream_t stream) {
    const float* x = (const float*)d_in[0];
    float* out = (float*)d_out;
    dim3 grid(B_DIM, NCHUNK);
    pcen_kernel<<<grid, 128, 0, stream>>>(x, out);
}

// Round 4
// 245.743 us; speedup vs baseline: 1.2151x; 1.0993x over previous
//
#include <hip/hip_runtime.h>

// PCEN: M[0]=x[0]; M[t]=(1-s)M[t-1]+s*x[t]; out=(x/(M+eps)^a + d)^r - d^r
// x, out: (64, 4000, 128) fp32.
//
// R4: exact blocked scan, 2 kernels (R3 post-mortem: wall tracks ISSUED bytes
// ~4.5 TB/s through L3, so kill the 3x warmup read amplification).
//  K1: per-(b,chunk) local zero-init scan, store chunk-end partial to ws (1 MB).
//  K2: exact carry-in from partials (A_C = 0.975^125), re-scan chunk, emit PCEN.
//      Output via nontemporal stores so the 128 MB write stream doesn't evict
//      the 131 MB x from the 256 MB L3 before K2's re-read.
// Linear recurrence algebra: M_end[k] = A_C * M_end[k-1] + B_end[k], k>=1;
// M_end[0] = B_end[0] (K1's ck=0 scan uses the exact M[0]=x[0] rule).

#define B_DIM 64
#define T_DIM 4000
#define F_DIM 128
#define NCHUNK 32
#define CLEN 125          // NCHUNK*CLEN == T_DIM
#define PF 25             // prefetch depth; CLEN = 5*PF
#define NG (CLEN / PF)    // 5 groups
#define A_C 0.04222576f   // 0.975^125, computed in double, rounded to fp32

__device__ __forceinline__ float pcen_out(float xv, float M) {
    const float EPS = 1e-6f, NALPHA = -0.98f, DELTA = 2.0f, SQRTD = 1.41421356237f;
    float p = __builtin_amdgcn_exp2f(NALPHA * __builtin_amdgcn_logf(M + EPS));
    return __builtin_sqrtf(__builtin_fmaf(xv, p, DELTA)) - SQRTD;
}

// ---- K1: chunk partials ----------------------------------------------------
__global__ __launch_bounds__(128) void pcen_partial(const float* __restrict__ x,
                                                    float* __restrict__ bend) {
    const float S = 0.025f, OMS = 0.975f;
    const int f  = threadIdx.x;          // lane = feature -> coalesced
    const int b  = blockIdx.x;
    const int ck = blockIdx.y;
    const int t0 = ck * CLEN;
    const float* xb = x + (size_t)b * T_DIM * F_DIM + f;
    const float first = (ck == 0) ? 1.0f : S;   // exact M[0]=x[0] rule in chunk 0

    float buf[PF];
    #pragma unroll
    for (int u = 0; u < PF; ++u) buf[u] = xb[(t0 + u) * F_DIM];

    float M = 0.0f;
    #pragma unroll
    for (int g = 0; g < NG; ++g) {
        #pragma unroll
        for (int u = 0; u < PF; ++u) {
            const int s = g * PF + u;
            const float xv = buf[u];
            const float ms = (s == 0) ? first : S;
            M = __builtin_fmaf(OMS, M, ms * xv);
            if (g + 1 < NG) buf[u] = xb[(t0 + s + PF) * F_DIM];
        }
    }
    bend[((size_t)b * NCHUNK + ck) * F_DIM + f] = M;   // chunk-end partial
}

// ---- K2: exact carry + emit ------------------------------------------------
__global__ __launch_bounds__(128) void pcen_emit(const float* __restrict__ x,
                                                 const float* __restrict__ bend,
                                                 float* __restrict__ out) {
    const float S = 0.025f, OMS = 0.975f;
    const int f  = threadIdx.x;
    const int b  = blockIdx.x;
    const int ck = blockIdx.y;
    const int t0 = ck * CLEN;
    const float* xb = x   + (size_t)b * T_DIM * F_DIM + f;
    float*       ob = out + (size_t)b * T_DIM * F_DIM + f;
    const float first = (ck == 0) ? 1.0f : S;

    // Issue main-loop prefetches first so they overlap the carry combine.
    float buf[PF];
    #pragma unroll
    for (int u = 0; u < PF; ++u) buf[u] = xb[(t0 + u) * F_DIM];

    // Exact carry-in: M_in = M_end[ck-1] from the 1 MB partials (L2-hot).
    float M = 0.0f;
    if (ck > 0) {
        const float* wb = bend + (size_t)b * NCHUNK * F_DIM + f;
        float Mc = wb[0];
        #pragma unroll 8
        for (int j = 1; j < ck; ++j)
            Mc = __builtin_fmaf(A_C, Mc, wb[(size_t)j * F_DIM]);
        M = Mc;
    }

    #pragma unroll
    for (int g = 0; g < NG; ++g) {
        #pragma unroll
        for (int u = 0; u < PF; ++u) {
            const int s = g * PF + u;
            const float xv = buf[u];
            const float ms = (s == 0) ? first : S;
            M = __builtin_fmaf(OMS, M, ms * xv);
            if (g + 1 < NG) buf[u] = xb[(t0 + s + PF) * F_DIM];
            // nontemporal: out is never re-read; keep x resident in L3
            __builtin_nontemporal_store(pcen_out(xv, M), &ob[(t0 + s) * F_DIM]);
        }
    }
}

extern "C" void kernel_launch(void* const* d_in, const int* in_sizes, int n_in,
                              void* d_out, int out_size, void* d_ws, size_t ws_size,
                              hipStream_t stream) {
    const float* x = (const float*)d_in[0];
    float* out  = (float*)d_out;
    float* bend = (float*)d_ws;   // 64*32*128 floats = 1 MB
    dim3 grid(B_DIM, NCHUNK);
    pcen_partial<<<grid, 128, 0, stream>>>(x, bend);
    pcen_emit   <<<grid, 128, 0, stream>>>(x, bend, out);
}